// Round 2
// baseline (1011.826 us; speedup 1.0000x reference)
//
#include <hip/hip_runtime.h>

// XSimGCL / LightGCN propagation on MI355X.
// Structure: per-launch CSR build (hist -> scan -> scatter), then 3x pull-SpMM
// (one wave per row, no fp32 atomics), selected-row accumulation, batched dot.

#define EMBED_DIM 64
#define NUM_LAYERS 3

// ---------------- CSR build ----------------

__global__ void hist_kernel(const int* __restrict__ rows, int* __restrict__ deg, int E) {
    int e = blockIdx.x * blockDim.x + threadIdx.x;
    if (e < E) atomicAdd(&deg[rows[e]], 1);
}

// tile = 1024 elements per block (256 threads x 4)
__global__ void scan1_kernel(const int* __restrict__ deg, int* __restrict__ row_ptr,
                             int* __restrict__ block_sums, int N) {
    __shared__ int lds[256];
    int tid  = threadIdx.x;
    int base = blockIdx.x * 1024 + tid * 4;
    int v[4];
    int s = 0;
#pragma unroll
    for (int k = 0; k < 4; ++k) {
        int i = base + k;
        v[k] = (i < N) ? deg[i] : 0;
        s += v[k];
    }
    lds[tid] = s;
    __syncthreads();
    for (int off = 1; off < 256; off <<= 1) {
        int t = (tid >= off) ? lds[tid - off] : 0;
        __syncthreads();
        lds[tid] += t;
        __syncthreads();
    }
    int run = lds[tid] - s;  // exclusive prefix of this thread's chunk
#pragma unroll
    for (int k = 0; k < 4; ++k) {
        int i = base + k;
        if (i < N) row_ptr[i] = run;
        run += v[k];
    }
    if (tid == 255) block_sums[blockIdx.x] = lds[255];
}

// single block, nb <= 256 tiles
__global__ void scan2_kernel(int* __restrict__ block_sums, int nb,
                             int* __restrict__ row_ptr, int N, int E) {
    __shared__ int lds[256];
    int tid = threadIdx.x;
    int v = (tid < nb) ? block_sums[tid] : 0;
    lds[tid] = v;
    __syncthreads();
    for (int off = 1; off < 256; off <<= 1) {
        int t = (tid >= off) ? lds[tid - off] : 0;
        __syncthreads();
        lds[tid] += t;
        __syncthreads();
    }
    if (tid < nb) block_sums[tid] = lds[tid] - v;  // exclusive
    if (tid == 0) row_ptr[N] = E;
}

__global__ void scan3_kernel(int* __restrict__ row_ptr, const int* __restrict__ block_sums, int N) {
    int i = blockIdx.x * blockDim.x + threadIdx.x;
    if (i < N) row_ptr[i] += block_sums[i >> 10];
}

__global__ void scatter_kernel(const int* __restrict__ rows, const int* __restrict__ cols,
                               const float* __restrict__ vals, int* __restrict__ cursor,
                               int* __restrict__ col_idx, float* __restrict__ col_val, int E) {
    int e = blockIdx.x * blockDim.x + threadIdx.x;
    if (e < E) {
        int r = rows[e];
        int p = atomicAdd(&cursor[r], 1);
        col_idx[p] = cols[e];
        col_val[p] = vals[e];
    }
}

// ---------------- SpMM (pull, one wave per row) ----------------

__global__ __launch_bounds__(256) void spmm_kernel(const int* __restrict__ row_ptr,
                                                   const int* __restrict__ col_idx,
                                                   const float* __restrict__ col_val,
                                                   const float* __restrict__ x,
                                                   float* __restrict__ y, int N) {
    int w    = (blockIdx.x * blockDim.x + threadIdx.x) >> 6;
    int lane = threadIdx.x & 63;
    if (w >= N) return;
    int s = row_ptr[w];
    int e = row_ptr[w + 1];
    float acc = 0.0f;
    int j = s;
    // unroll-4 for gather ILP
    for (; j + 3 < e; j += 4) {
        int   c0 = col_idx[j],     c1 = col_idx[j + 1];
        int   c2 = col_idx[j + 2], c3 = col_idx[j + 3];
        float v0 = col_val[j],     v1 = col_val[j + 1];
        float v2 = col_val[j + 2], v3 = col_val[j + 3];
        float x0 = x[(size_t)c0 * EMBED_DIM + lane];
        float x1 = x[(size_t)c1 * EMBED_DIM + lane];
        float x2 = x[(size_t)c2 * EMBED_DIM + lane];
        float x3 = x[(size_t)c3 * EMBED_DIM + lane];
        acc += v0 * x0;
        acc += v1 * x1;
        acc += v2 * x2;
        acc += v3 * x3;
    }
    for (; j < e; ++j) acc += col_val[j] * x[(size_t)col_idx[j] * EMBED_DIM + lane];
    y[(size_t)w * EMBED_DIM + lane] = acc;
}

// ---------------- readout ----------------

__global__ void add_sel_kernel(const float* __restrict__ y, const int* __restrict__ user_ids,
                               const int* __restrict__ item_ids, float* __restrict__ acc_sel,
                               int B, int U) {
    int w    = (blockIdx.x * blockDim.x + threadIdx.x) >> 6;
    int lane = threadIdx.x & 63;
    if (w >= 2 * B) return;
    int row = (w < B) ? user_ids[w] : (item_ids[w - B] + U);
    acc_sel[(size_t)w * EMBED_DIM + lane] += y[(size_t)row * EMBED_DIM + lane];
}

__global__ void dot_kernel(const float* __restrict__ acc_sel, float* __restrict__ out, int B) {
    int w    = (blockIdx.x * blockDim.x + threadIdx.x) >> 6;
    int lane = threadIdx.x & 63;
    if (w >= B) return;
    float p = acc_sel[(size_t)w * EMBED_DIM + lane] * acc_sel[(size_t)(B + w) * EMBED_DIM + lane];
#pragma unroll
    for (int off = 32; off > 0; off >>= 1) p += __shfl_down(p, off, 64);
    if (lane == 0) out[w] = p * (1.0f / (NUM_LAYERS * NUM_LAYERS));
}

// ---------------- launch ----------------

extern "C" void kernel_launch(void* const* d_in, const int* in_sizes, int n_in,
                              void* d_out, int out_size, void* d_ws, size_t ws_size,
                              hipStream_t stream) {
    const float* user_emb = (const float*)d_in[0];
    const float* item_emb = (const float*)d_in[1];
    const float* vals     = (const float*)d_in[2];
    const int*   rows     = (const int*)d_in[3];
    const int*   cols     = (const int*)d_in[4];
    const int*   user_ids = (const int*)d_in[5];
    const int*   item_ids = (const int*)d_in[6];
    float*       out      = (float*)d_out;

    const int U = in_sizes[0] / EMBED_DIM;
    const int I = in_sizes[1] / EMBED_DIM;
    const int E = in_sizes[2];
    const int B = in_sizes[5];
    const int N = U + I;

    // workspace layout
    char* w = (char*)d_ws;
    float* x       = (float*)w; w += (size_t)N * EMBED_DIM * sizeof(float);
    float* y       = (float*)w; w += (size_t)N * EMBED_DIM * sizeof(float);
    float* col_val = (float*)w; w += (size_t)E * sizeof(float);
    int*   col_idx = (int*)w;   w += (size_t)E * sizeof(int);
    int*   deg     = (int*)w;   w += (size_t)N * sizeof(int);
    int*   row_ptr = (int*)w;   w += (size_t)(N + 1) * sizeof(int);
    int*   cursor  = (int*)w;   w += (size_t)N * sizeof(int);
    int*   bsums   = (int*)w;   w += 1024 * sizeof(int);
    float* acc_sel = (float*)w; w += (size_t)2 * B * EMBED_DIM * sizeof(float);

    const int T = 256;
    const int nb_tiles = (N + 1023) / 1024;

    // init: x = concat(user_emb, item_emb); deg = 0; acc_sel = 0
    hipMemcpyAsync(x, user_emb, (size_t)U * EMBED_DIM * sizeof(float),
                   hipMemcpyDeviceToDevice, stream);
    hipMemcpyAsync(x + (size_t)U * EMBED_DIM, item_emb, (size_t)I * EMBED_DIM * sizeof(float),
                   hipMemcpyDeviceToDevice, stream);
    hipMemsetAsync(deg, 0, (size_t)N * sizeof(int), stream);
    hipMemsetAsync(acc_sel, 0, (size_t)2 * B * EMBED_DIM * sizeof(float), stream);

    // CSR build
    hist_kernel<<<(E + T - 1) / T, T, 0, stream>>>(rows, deg, E);
    scan1_kernel<<<nb_tiles, T, 0, stream>>>(deg, row_ptr, bsums, N);
    scan2_kernel<<<1, T, 0, stream>>>(bsums, nb_tiles, row_ptr, N, E);
    scan3_kernel<<<(N + T - 1) / T, T, 0, stream>>>(row_ptr, bsums, N);
    hipMemcpyAsync(cursor, row_ptr, (size_t)N * sizeof(int), hipMemcpyDeviceToDevice, stream);
    scatter_kernel<<<(E + T - 1) / T, T, 0, stream>>>(rows, cols, vals, cursor, col_idx, col_val, E);

    // 3 propagation layers, ping-pong x<->y
    float* cur = x;
    float* nxt = y;
    for (int layer = 0; layer < NUM_LAYERS; ++layer) {
        spmm_kernel<<<(N * 64 + T - 1) / T, T, 0, stream>>>(row_ptr, col_idx, col_val, cur, nxt, N);
        add_sel_kernel<<<(2 * B * 64 + T - 1) / T, T, 0, stream>>>(nxt, user_ids, item_ids,
                                                                   acc_sel, B, U);
        float* tmp = cur; cur = nxt; nxt = tmp;
    }

    // out[b] = dot(accU[b], accI[b]) / 9
    dot_kernel<<<(B * 64 + T - 1) / T, T, 0, stream>>>(acc_sel, out, B);
}